// Round 1
// baseline (636.048 us; speedup 1.0000x reference)
//
#include <hip/hip_runtime.h>
#include <hip/hip_cooperative_groups.h>
#include <math.h>

namespace cg = cooperative_groups;

#define N_NODES 100000
#define N_EDGES 3200000
#define IN_DIM 128
#define HG 64

#define E0CAP 2048      // capacity for edges into node 0 (expected ~32)
#define MCAP  65536     // capacity for edges into S1 nodes (expected ~1100)
#define NBMW  3125      // bitmap words: ceil(100000/32)
#define SCAN_BLOCKS 1024  // fallback path grid
#define BLK_E0 16       // per-block capacity for dst==0 hits

// fused cooperative kernel geometry
#define NBLK 512
#define NTHR 256

// workspace layout; [0, WS_ZERO_BYTES) zeroed by phase A / k_scan0
#define OFF_DEG       0u          // int[N_NODES]            400000
#define OFF_SLOTMAP   400000u     // int[N_NODES]            400000
#define OFF_CNT       800000u     // int[8]: n0,ns,m         32
#define OFF_ACC       800032u     // float[E0CAP*HG]         524288
#define OFF_BMS1      1324320u    // uint[NBMW] pad          12544
#define OFF_BMNEED    1336864u    // uint[NBMW] pad          12544
#define WS_ZERO_BYTES 1349408u
#define OFF_BCNT      1349408u    // int[SCAN_BLOCKS]        4096
#define OFF_BLIST     1353504u    // int[SCAN_BLOCKS*BLK_E0] 65536
#define OFF_EDGES0    1419040u    // int[E0CAP]              8192
#define OFF_SLOTNODE  1427232u    // int[E0CAP]              8192
#define OFF_MLISTS    1435424u    // int[MCAP]  s | slot<<17 262144
#define OFF_MLISTD    1697568u    // int[MCAP]  d            262144

#define CHUNK 256

__device__ __forceinline__ float dinv_of(int degv) {
    // reference: deg = indeg + 1 (self loop), dinv = 1/sqrt(deg), always >= 1
    return 1.0f / sqrtf((float)(degv + 1));
}

// ===========================================================================
// Fused cooperative kernel: all six passes with grid.sync() between phases.
// Launch/drain gaps were the dominant controllable cost (work itself ~25-35us,
// L3-resident scans). 512 blocks x 256 thr guaranteed co-resident
// (17.5 KB LDS, launch_bounds(256,2)); residency validated by the coop API.
// ===========================================================================
__global__ void __launch_bounds__(NTHR, 2)
k_fused(const int* __restrict__ src, const int* __restrict__ dst,
        const float* __restrict__ x, const float* __restrict__ W1,
        const float* __restrict__ b1, const float* __restrict__ W2,
        const float* __restrict__ b2, const float* __restrict__ w_ih,
        const float* __restrict__ b_ih, const float* __restrict__ b_hh,
        const float* __restrict__ fc_w, const float* __restrict__ fc_b,
        char* __restrict__ ws, float* __restrict__ out)
{
    int*      deg       = (int*)(ws + OFF_DEG);
    int*      slotmap   = (int*)(ws + OFF_SLOTMAP);
    int*      cnt       = (int*)(ws + OFF_CNT);
    float*    acc       = (float*)(ws + OFF_ACC);
    unsigned* bmS1      = (unsigned*)(ws + OFF_BMS1);
    unsigned* bmNeed    = (unsigned*)(ws + OFF_BMNEED);
    int*      bcnt      = (int*)(ws + OFF_BCNT);
    int*      blist     = (int*)(ws + OFF_BLIST);
    int*      edges0    = (int*)(ws + OFF_EDGES0);
    int*      slotnodes = (int*)(ws + OFF_SLOTNODE);
    int*      mlistS    = (int*)(ws + OFF_MLISTS);
    int*      mlistD    = (int*)(ws + OFF_MLISTD);

    cg::grid_group grid = cg::this_grid();

    __shared__ unsigned sbm[NBMW];    // 12.5 KB, reused phase C -> D
    __shared__ int lcnt;
    __shared__ int lsrc[BLK_E0];
    __shared__ int   sh_sl[CHUNK];
    __shared__ float sh_w[CHUNK];
    __shared__ float partial[4][HG];
    __shared__ float aggv[HG];
    __shared__ float zv[HG];
    __shared__ float gates[4 * HG];
    __shared__ float hw[HG];

    const int bid = blockIdx.x;
    const int t   = threadIdx.x;
    const int tid = bid * NTHR + t;
    const int nth = NBLK * NTHR;

    // ---- Phase A: zero ws (replaces memset; ws is re-poisoned by harness)
    //      + scan dst for edges into node 0, per-block LDS compaction ----
    if (t == 0) lcnt = 0;
    __syncthreads();
    {
        int4 z; z.x = 0; z.y = 0; z.z = 0; z.w = 0;
        int4* zb = (int4*)ws;
        const int nz = WS_ZERO_BYTES / 16;
        for (int i = tid; i < nz; i += nth) zb[i] = z;
        const int4* dst4 = (const int4*)dst;
        const int n4 = N_EDGES / 4;
        for (int i = tid; i < n4; i += nth) {
            int4 dv = dst4[i];
            int ds[4] = {dv.x, dv.y, dv.z, dv.w};
#pragma unroll
            for (int k = 0; k < 4; k++) {
                if (ds[k] == 0) {
                    int p = atomicAdd(&lcnt, 1);
                    if (p < BLK_E0) lsrc[p] = src[4 * i + k];
                }
            }
        }
    }
    __syncthreads();
    {
        int c = lcnt; if (c > BLK_E0) c = BLK_E0;
        if (t == 0) bcnt[bid] = c;
        for (int i = t; i < c; i += NTHR) blist[bid * BLK_E0 + i] = lsrc[i];
    }
    __threadfence();
    grid.sync();

    // ---- Phase B: block 0 gathers lists -> edges0, dedupes -> slots, bmS1 ----
    if (bid == 0) {
        for (int b = t; b < NBLK; b += NTHR) {
            int c = bcnt[b];
            if (c > 0) {
                int p = atomicAdd(&cnt[0], c);
                for (int j = 0; j < c && p + j < E0CAP; j++)
                    edges0[p + j] = blist[b * BLK_E0 + j];
            }
        }
        __syncthreads();
        int n0 = atomicAdd(&cnt[0], 0); if (n0 > E0CAP) n0 = E0CAP;
        for (int i = t; i < n0 + 1; i += NTHR) {
            int s = (i == n0) ? 0 : edges0[i];   // +node 0 itself
            if (atomicCAS(&slotmap[s], 0, 1) == 0) {
                int p = atomicAdd(&cnt[1], 1);
                if (p < E0CAP) slotnodes[p] = s;
            }
        }
        __syncthreads();
        int ns = atomicAdd(&cnt[1], 0); if (ns > E0CAP) ns = E0CAP;
        for (int i = t; i < ns; i += NTHR) {
            int s = slotnodes[i];
            slotmap[s] = i + 1;
            atomicOr(&bmS1[s >> 5], 1u << (s & 31));
        }
    }
    __threadfence();
    grid.sync();

    // ---- Phase C: LDS-bitmap probe for dst in S1 -> packed task records ----
    for (int i = t; i < NBMW; i += NTHR) sbm[i] = bmS1[i];
    __syncthreads();
    {
        const int4* dst4 = (const int4*)dst;
        const int n4 = N_EDGES / 4;
        for (int i = tid; i < n4; i += nth) {
            int4 dv = dst4[i];
            unsigned ds[4] = {(unsigned)dv.x, (unsigned)dv.y,
                              (unsigned)dv.z, (unsigned)dv.w};
#pragma unroll
            for (int k = 0; k < 4; k++) {
                unsigned d = ds[k];
                if ((sbm[d >> 5] >> (d & 31)) & 1u) {
                    int e = 4 * i + k;
                    int s = src[e];
                    int sl = slotmap[d] - 1;
                    int p = atomicAdd(&cnt[2], 1);
                    if (p < MCAP) {
                        mlistS[p] = s | (sl << 17);
                        mlistD[p] = (int)d;
                    }
                    atomicOr(&bmNeed[s >> 5], 1u << (s & 31));
                }
            }
        }
    }
    __threadfence();
    grid.sync();

    // ---- Phase D: filtered in-degree; reuse sbm, just OR in bmNeed ----
    for (int i = t; i < NBMW; i += NTHR) sbm[i] |= bmNeed[i];
    __syncthreads();
    {
        const int4* dst4 = (const int4*)dst;
        const int n4 = N_EDGES / 4;
        for (int i = tid; i < n4; i += nth) {
            int4 dv = dst4[i];
            unsigned ds[4] = {(unsigned)dv.x, (unsigned)dv.y,
                              (unsigned)dv.z, (unsigned)dv.w};
#pragma unroll
            for (int k = 0; k < 4; k++) {
                unsigned d = ds[k];
                if ((sbm[d >> 5] >> (d & 31)) & 1u) atomicAdd(&deg[d], 1);
            }
        }
    }
    __threadfence();
    grid.sync();

    // ---- Phase E: edge contributions; 4 wave-tasks per 256-thr block ----
    {
        int m = cnt[2]; if (m > MCAP) m = MCAP;
        int ns = cnt[1]; if (ns > E0CAP) ns = E0CAP;
        const int vtotal = 2 * (m + ns);
        const int j = t & 63;        // output channel
        const int grp = t >> 6;      // wave within block
        for (int v = bid * 4 + grp; v < vtotal; v += NBLK * 4) {
            const int ii = v >> 1;
            const int kbase = (v & 1) << 6;  // 0 or 64
            int s, sl;
            float w;
            if (ii < m) {
                int sw = mlistS[ii];
                int d = mlistD[ii];
                s = sw & 0x1FFFF;
                sl = sw >> 17;
                w = dinv_of(deg[s]) * dinv_of(deg[d]);
            } else {
                sl = ii - m;
                s = slotnodes[sl];
                float dv = dinv_of(deg[s]);
                w = dv * dv;
            }
            const float* xp = x + (size_t)kbase * N_NODES + s;
            const float* wp = W1 + kbase * HG + j;
            float g = 0.f;
#pragma unroll
            for (int k = 0; k < 64; k++) {
                g = fmaf(xp[(size_t)k * N_NODES], wp[k * HG], g);
            }
            atomicAdd(&acc[sl * HG + j], g * w);
        }
    }
    __threadfence();
    grid.sync();

    // ---- Phase F: block 0: layer-2 agg at node 0, W2, LSTM, FC ----
    if (bid == 0) {
        const int ch = t & (HG - 1);
        const int grp = t >> 6;
        int n0 = cnt[0]; if (n0 > E0CAP) n0 = E0CAP;

        const float dinv0 = dinv_of(deg[0]);
        const float bch = b1[ch];

        float a = 0.f;
        for (int base = 0; base < n0; base += CHUNK) {
            int cn = n0 - base; if (cn > CHUNK) cn = CHUNK;
            __syncthreads();
            if (t < cn) {
                int s = edges0[base + t];
                sh_sl[t] = slotmap[s] - 1;
                sh_w[t] = dinv_of(deg[s]) * dinv0;
            }
            __syncthreads();
            for (int i = grp; i < cn; i += 4) {
                float h = acc[sh_sl[i] * HG + ch] + bch;
                a = fmaf(sh_w[i], (h > 0.f ? h : 0.f), a);
            }
        }
        partial[grp][ch] = a;
        __syncthreads();
        if (t < HG) {
            int sl0 = slotmap[0] - 1;
            float h0 = acc[sl0 * HG + t] + b1[t];
            float sg = dinv0 * dinv0 * (h0 > 0.f ? h0 : 0.f);
            sg += partial[0][t] + partial[1][t] + partial[2][t] + partial[3][t];
            aggv[t] = sg;
        }
        __syncthreads();

        if (t < HG) {
            float zz = b2[t];
#pragma unroll 8
            for (int k = 0; k < HG; k++) zz = fmaf(aggv[k], W2[k * HG + t], zz);
            zv[t] = zz;
        }
        __syncthreads();

        {
            float gt = b_ih[t] + b_hh[t];
#pragma unroll 8
            for (int jj = 0; jj < HG; jj++) gt = fmaf(zv[jj], w_ih[t * HG + jj], gt);
            gates[t] = gt;
        }
        __syncthreads();

        if (t < HG) {
            float ig = 1.f / (1.f + expf(-gates[t]));
            float gg = tanhf(gates[2 * HG + t]);
            float og = 1.f / (1.f + expf(-gates[3 * HG + t]));
            float c = ig * gg;
            float hy = og * tanhf(c);
            hw[t] = hy * fc_w[t];
        }
        __syncthreads();
        if (t == 0) {
            float y = fc_b[0];
            for (int jj = 0; jj < HG; jj++) y += hw[jj];
            out[0] = y;
        }
    }
}

// ===========================================================================
// Fallback path: the proven 6-kernel pipeline (unchanged), used only if the
// cooperative launch is rejected (e.g. unsupported under stream capture).
// ===========================================================================
__global__ void k_scan0(const int* __restrict__ src, const int* __restrict__ dst,
                        int4* __restrict__ zbase, int* __restrict__ bcnt,
                        int* __restrict__ blist) {
    __shared__ int lcnt;
    __shared__ int lsrc[BLK_E0];
    if (threadIdx.x == 0) lcnt = 0;
    __syncthreads();
    int tid = blockIdx.x * blockDim.x + threadIdx.x;
    int nth = gridDim.x * blockDim.x;
    const int nz = WS_ZERO_BYTES / 16;
    int4 z; z.x = 0; z.y = 0; z.z = 0; z.w = 0;
    for (int i = tid; i < nz; i += nth) zbase[i] = z;
    const int4* dst4 = (const int4*)dst;
    const int n4 = N_EDGES / 4;
    for (int i = tid; i < n4; i += nth) {
        int4 dv = dst4[i];
        int ds[4] = {dv.x, dv.y, dv.z, dv.w};
#pragma unroll
        for (int k = 0; k < 4; k++) {
            if (ds[k] == 0) {
                int p = atomicAdd(&lcnt, 1);
                if (p < BLK_E0) lsrc[p] = src[4 * i + k];
            }
        }
    }
    __syncthreads();
    int c = lcnt; if (c > BLK_E0) c = BLK_E0;
    if (threadIdx.x == 0) bcnt[blockIdx.x] = c;
    for (int i = threadIdx.x; i < c; i += blockDim.x)
        blist[blockIdx.x * BLK_E0 + i] = lsrc[i];
}

__global__ void k_build_slots(const int* __restrict__ bcnt, const int* __restrict__ blist,
                              int* __restrict__ edges0, int* __restrict__ slotnodes,
                              int* __restrict__ slotmap, int* __restrict__ cnt,
                              unsigned* __restrict__ bmS1) {
    const int t = threadIdx.x;
    for (int b = t; b < SCAN_BLOCKS; b += blockDim.x) {
        int c = bcnt[b];
        if (c > 0) {
            int p = atomicAdd(&cnt[0], c);
            for (int j = 0; j < c && p + j < E0CAP; j++)
                edges0[p + j] = blist[b * BLK_E0 + j];
        }
    }
    __syncthreads();
    int n0 = atomicAdd(&cnt[0], 0); if (n0 > E0CAP) n0 = E0CAP;
    for (int i = t; i < n0 + 1; i += blockDim.x) {
        int s = (i == n0) ? 0 : edges0[i];
        if (atomicCAS(&slotmap[s], 0, 1) == 0) {
            int p = atomicAdd(&cnt[1], 1);
            if (p < E0CAP) slotnodes[p] = s;
        }
    }
    __syncthreads();
    int ns = atomicAdd(&cnt[1], 0); if (ns > E0CAP) ns = E0CAP;
    for (int i = t; i < ns; i += blockDim.x) {
        int s = slotnodes[i];
        slotmap[s] = i + 1;
        atomicOr(&bmS1[s >> 5], 1u << (s & 31));
    }
}

__global__ void k_match(const int* __restrict__ src, const int* __restrict__ dst,
                        const int* __restrict__ slotmap,
                        const unsigned* __restrict__ bmS1, unsigned* __restrict__ bmNeed,
                        int* __restrict__ cnt, int* __restrict__ mlistS,
                        int* __restrict__ mlistD) {
    __shared__ unsigned sbm[NBMW];
    for (int i = threadIdx.x; i < NBMW; i += blockDim.x) sbm[i] = bmS1[i];
    __syncthreads();
    int tid = blockIdx.x * blockDim.x + threadIdx.x;
    int nth = gridDim.x * blockDim.x;
    const int4* dst4 = (const int4*)dst;
    const int n4 = N_EDGES / 4;
    for (int i = tid; i < n4; i += nth) {
        int4 dv = dst4[i];
        unsigned ds[4] = {(unsigned)dv.x, (unsigned)dv.y, (unsigned)dv.z, (unsigned)dv.w};
#pragma unroll
        for (int k = 0; k < 4; k++) {
            unsigned d = ds[k];
            if ((sbm[d >> 5] >> (d & 31)) & 1u) {
                int e = 4 * i + k;
                int s = src[e];
                int sl = slotmap[d] - 1;
                int p = atomicAdd(&cnt[2], 1);
                if (p < MCAP) {
                    mlistS[p] = s | (sl << 17);
                    mlistD[p] = (int)d;
                }
                atomicOr(&bmNeed[s >> 5], 1u << (s & 31));
            }
        }
    }
}

__global__ void k_deg_need(const int* __restrict__ dst, const unsigned* __restrict__ bmS1,
                           const unsigned* __restrict__ bmNeed, int* __restrict__ deg) {
    __shared__ unsigned sbm[NBMW];
    for (int i = threadIdx.x; i < NBMW; i += blockDim.x) sbm[i] = bmS1[i] | bmNeed[i];
    __syncthreads();
    int tid = blockIdx.x * blockDim.x + threadIdx.x;
    int nth = gridDim.x * blockDim.x;
    const int4* dst4 = (const int4*)dst;
    const int n4 = N_EDGES / 4;
    for (int i = tid; i < n4; i += nth) {
        int4 dv = dst4[i];
        unsigned ds[4] = {(unsigned)dv.x, (unsigned)dv.y, (unsigned)dv.z, (unsigned)dv.w};
#pragma unroll
        for (int k = 0; k < 4; k++) {
            unsigned d = ds[k];
            if ((sbm[d >> 5] >> (d & 31)) & 1u) atomicAdd(&deg[d], 1);
        }
    }
}

__global__ void k_contrib(const int* __restrict__ deg, const int* __restrict__ cnt,
                          const int* __restrict__ mlistS, const int* __restrict__ mlistD,
                          const int* __restrict__ slotnodes,
                          const float* __restrict__ x, const float* __restrict__ W1,
                          float* __restrict__ acc) {
    int m = cnt[2]; if (m > MCAP) m = MCAP;
    int ns = cnt[1]; if (ns > E0CAP) ns = E0CAP;
    const int vtotal = 2 * (m + ns);
    const int j = threadIdx.x;
    for (int v = blockIdx.x; v < vtotal; v += gridDim.x) {
        const int ii = v >> 1;
        const int kbase = (v & 1) << 6;
        int s, sl;
        float w;
        if (ii < m) {
            int sw = mlistS[ii];
            int d = mlistD[ii];
            s = sw & 0x1FFFF;
            sl = sw >> 17;
            w = dinv_of(deg[s]) * dinv_of(deg[d]);
        } else {
            sl = ii - m;
            s = slotnodes[sl];
            float dv = dinv_of(deg[s]);
            w = dv * dv;
        }
        const float* xp = x + (size_t)kbase * N_NODES + s;
        const float* wp = W1 + kbase * HG + j;
        float g = 0.f;
#pragma unroll
        for (int k = 0; k < 64; k++) {
            g = fmaf(xp[(size_t)k * N_NODES], wp[k * HG], g);
        }
        atomicAdd(&acc[sl * HG + j], g * w);
    }
}

__global__ void k_final(const float* __restrict__ b1, const float* __restrict__ W2,
                        const float* __restrict__ b2, const float* __restrict__ w_ih,
                        const float* __restrict__ b_ih, const float* __restrict__ b_hh,
                        const float* __restrict__ fc_w, const float* __restrict__ fc_b,
                        const int* __restrict__ deg, const int* __restrict__ slotmap,
                        const int* __restrict__ cnt, const int* __restrict__ edges0,
                        const float* __restrict__ acc, float* __restrict__ out) {
    __shared__ int   sh_sl[CHUNK];
    __shared__ float sh_w[CHUNK];
    __shared__ float partial[4][HG];
    __shared__ float agg[HG];
    __shared__ float zv[HG];
    __shared__ float gates[4 * HG];
    __shared__ float hw[HG];
    const int t = threadIdx.x;
    const int ch = t & (HG - 1);
    const int grp = t >> 6;
    int n0 = cnt[0]; if (n0 > E0CAP) n0 = E0CAP;

    const float dinv0 = dinv_of(deg[0]);
    const float bch = b1[ch];

    float a = 0.f;
    for (int base = 0; base < n0; base += CHUNK) {
        int cn = n0 - base; if (cn > CHUNK) cn = CHUNK;
        __syncthreads();
        if (t < cn) {
            int s = edges0[base + t];
            sh_sl[t] = slotmap[s] - 1;
            sh_w[t] = dinv_of(deg[s]) * dinv0;
        }
        __syncthreads();
        for (int i = grp; i < cn; i += 4) {
            float h = acc[sh_sl[i] * HG + ch] + bch;
            a = fmaf(sh_w[i], (h > 0.f ? h : 0.f), a);
        }
    }
    partial[grp][ch] = a;
    __syncthreads();
    if (t < HG) {
        int sl0 = slotmap[0] - 1;
        float h0 = acc[sl0 * HG + t] + b1[t];
        float s = dinv0 * dinv0 * (h0 > 0.f ? h0 : 0.f);
        s += partial[0][t] + partial[1][t] + partial[2][t] + partial[3][t];
        agg[t] = s;
    }
    __syncthreads();

    if (t < HG) {
        float zz = b2[t];
#pragma unroll 8
        for (int k = 0; k < HG; k++) zz = fmaf(agg[k], W2[k * HG + t], zz);
        zv[t] = zz;
    }
    __syncthreads();

    {
        float gt = b_ih[t] + b_hh[t];
#pragma unroll 8
        for (int jj = 0; jj < HG; jj++) gt = fmaf(zv[jj], w_ih[t * HG + jj], gt);
        gates[t] = gt;
    }
    __syncthreads();

    if (t < HG) {
        float ig = 1.f / (1.f + expf(-gates[t]));
        float gg = tanhf(gates[2 * HG + t]);
        float og = 1.f / (1.f + expf(-gates[3 * HG + t]));
        float c = ig * gg;
        float hy = og * tanhf(c);
        hw[t] = hy * fc_w[t];
    }
    __syncthreads();
    if (t == 0) {
        float y = fc_b[0];
        for (int jj = 0; jj < HG; jj++) y += hw[jj];
        out[0] = y;
    }
}

extern "C" void kernel_launch(void* const* d_in, const int* in_sizes, int n_in,
                              void* d_out, int out_size, void* d_ws, size_t ws_size,
                              hipStream_t stream) {
    const float* x    = (const float*)d_in[0];
    const int*   ei   = (const int*)d_in[1];
    const float* W1   = (const float*)d_in[2];
    const float* b1   = (const float*)d_in[3];
    const float* W2   = (const float*)d_in[4];
    const float* b2   = (const float*)d_in[5];
    const float* w_ih = (const float*)d_in[6];
    // d_in[7] = w_hh, unused (h0 = 0)
    const float* b_ih = (const float*)d_in[8];
    const float* b_hh = (const float*)d_in[9];
    const float* fc_w = (const float*)d_in[10];
    const float* fc_b = (const float*)d_in[11];
    float* out = (float*)d_out;

    const int* src = ei;
    const int* dst = ei + N_EDGES;
    char* ws = (char*)d_ws;

    void* args[] = {(void*)&src, (void*)&dst, (void*)&x, (void*)&W1, (void*)&b1,
                    (void*)&W2, (void*)&b2, (void*)&w_ih, (void*)&b_ih,
                    (void*)&b_hh, (void*)&fc_w, (void*)&fc_b, (void*)&ws, (void*)&out};
    hipError_t err = hipLaunchCooperativeKernel((const void*)k_fused, dim3(NBLK),
                                                dim3(NTHR), args, 0, stream);

    if (err != hipSuccess) {
        // fallback: proven 6-kernel pipeline
        int*      deg       = (int*)(ws + OFF_DEG);
        int*      slotmap   = (int*)(ws + OFF_SLOTMAP);
        int*      cnt       = (int*)(ws + OFF_CNT);
        float*    acc       = (float*)(ws + OFF_ACC);
        unsigned* bmS1      = (unsigned*)(ws + OFF_BMS1);
        unsigned* bmNeed    = (unsigned*)(ws + OFF_BMNEED);
        int*      bcnt      = (int*)(ws + OFF_BCNT);
        int*      blist     = (int*)(ws + OFF_BLIST);
        int*      edges0    = (int*)(ws + OFF_EDGES0);
        int*      slotnodes = (int*)(ws + OFF_SLOTNODE);
        int*      mlistS    = (int*)(ws + OFF_MLISTS);
        int*      mlistD    = (int*)(ws + OFF_MLISTD);

        k_scan0<<<SCAN_BLOCKS, 256, 0, stream>>>(src, dst, (int4*)ws, bcnt, blist);
        k_build_slots<<<1, 256, 0, stream>>>(bcnt, blist, edges0, slotnodes, slotmap,
                                             cnt, bmS1);
        k_match<<<SCAN_BLOCKS, 256, 0, stream>>>(src, dst, slotmap, bmS1, bmNeed, cnt,
                                                 mlistS, mlistD);
        k_deg_need<<<SCAN_BLOCKS, 256, 0, stream>>>(dst, bmS1, bmNeed, deg);
        k_contrib<<<4096, 64, 0, stream>>>(deg, cnt, mlistS, mlistD, slotnodes, x, W1, acc);
        k_final<<<1, 256, 0, stream>>>(b1, W2, b2, w_ih, b_ih, b_hh, fc_w, fc_b,
                                       deg, slotmap, cnt, edges0, acc, out);
    }
}

// Round 2
// 247.973 us; speedup vs baseline: 2.5650x; 2.5650x over previous
//
#include <hip/hip_runtime.h>
#include <math.h>

#define N_NODES 100000
#define N_EDGES 3200000
#define IN_DIM 128
#define HG 64

#define E0CAP 2048      // capacity for edges into node 0 (expected ~32)
#define MCAP  65536     // capacity for edges into S1 nodes (expected ~1100)
#define NBMW  3125      // bitmap words: ceil(100000/32)
#define SCAN_BLOCKS 256 // 1 block/CU; bitmap LDS traffic = 256*12.5KB = 3.2MB (was 12.8MB @1024)
#define BLK_E0 16       // per-block capacity for dst==0 hits (expected ~0.125 @256 blocks)
#define CF_BLOCKS 1024  // contrib+final grid: 4 wave-tasks per block

// workspace layout; [0, WS_ZERO_BYTES) zeroed by k_scan0 grid-stride
#define OFF_DEG       0u          // int[N_NODES]            400000
#define OFF_SLOTMAP   400000u     // int[N_NODES]            400000
#define OFF_CNT       800000u     // int[8]: n0,ns,m,done    32
#define OFF_ACC       800032u     // float[E0CAP*HG]         524288
#define OFF_BMS1      1324320u    // uint[NBMW] pad          12544
#define OFF_BMNEED    1336864u    // uint[NBMW] pad          12544
#define WS_ZERO_BYTES 1349408u
#define OFF_BCNT      1349408u    // int[SCAN_BLOCKS] (cap 1024) 4096
#define OFF_BLIST     1353504u    // int[1024*BLK_E0]        65536
#define OFF_EDGES0    1419040u    // int[E0CAP]              8192
#define OFF_SLOTNODE  1427232u    // int[E0CAP]              8192
#define OFF_MLISTS    1435424u    // int[MCAP]  s | slot<<17 262144
#define OFF_MLISTD    1697568u    // int[MCAP]  d            262144

#define CHUNK 256

__device__ __forceinline__ float dinv_of(int degv) {
    // reference: deg = indeg + 1 (self loop), dinv = 1/sqrt(deg), always >= 1
    return 1.0f / sqrtf((float)(degv + 1));
}

// Pass 1: zero ws counters/acc/bitmaps (replaces hipMemsetAsync) and scan dst
// for edges into node 0, compacting per-block (no global counter).
__global__ void k_scan0(const int* __restrict__ src, const int* __restrict__ dst,
                        int4* __restrict__ zbase, int* __restrict__ bcnt,
                        int* __restrict__ blist) {
    __shared__ int lcnt;
    __shared__ int lsrc[BLK_E0];
    if (threadIdx.x == 0) lcnt = 0;
    __syncthreads();
    int tid = blockIdx.x * blockDim.x + threadIdx.x;
    int nth = gridDim.x * blockDim.x;
    const int nz = WS_ZERO_BYTES / 16;
    int4 z; z.x = 0; z.y = 0; z.z = 0; z.w = 0;
    for (int i = tid; i < nz; i += nth) zbase[i] = z;
    const int4* dst4 = (const int4*)dst;
    const int n4 = N_EDGES / 4;
    for (int i = tid; i < n4; i += nth) {
        int4 dv = dst4[i];
        int ds[4] = {dv.x, dv.y, dv.z, dv.w};
#pragma unroll
        for (int k = 0; k < 4; k++) {
            if (ds[k] == 0) {
                int p = atomicAdd(&lcnt, 1);
                if (p < BLK_E0) lsrc[p] = src[4 * i + k];
            }
        }
    }
    __syncthreads();
    int c = lcnt; if (c > BLK_E0) c = BLK_E0;
    if (threadIdx.x == 0) bcnt[blockIdx.x] = c;
    for (int i = threadIdx.x; i < c; i += blockDim.x)
        blist[blockIdx.x * BLK_E0 + i] = lsrc[i];
}

// Pass 2 (1 block): gather per-block lists -> dense edges0, dedupe -> slots,
// build S1 bitmap.
__global__ void k_build_slots(const int* __restrict__ bcnt, const int* __restrict__ blist,
                              int* __restrict__ edges0, int* __restrict__ slotnodes,
                              int* __restrict__ slotmap, int* __restrict__ cnt,
                              unsigned* __restrict__ bmS1) {
    const int t = threadIdx.x;
    for (int b = t; b < SCAN_BLOCKS; b += blockDim.x) {
        int c = bcnt[b];
        if (c > 0) {
            int p = atomicAdd(&cnt[0], c);
            for (int j = 0; j < c && p + j < E0CAP; j++)
                edges0[p + j] = blist[b * BLK_E0 + j];
        }
    }
    __syncthreads();
    int n0 = atomicAdd(&cnt[0], 0); if (n0 > E0CAP) n0 = E0CAP;
    for (int i = t; i < n0 + 1; i += blockDim.x) {
        int s = (i == n0) ? 0 : edges0[i];   // +node 0 itself
        if (atomicCAS(&slotmap[s], 0, 1) == 0) {
            int p = atomicAdd(&cnt[1], 1);
            if (p < E0CAP) slotnodes[p] = s;
        }
    }
    __syncthreads();
    int ns = atomicAdd(&cnt[1], 0); if (ns > E0CAP) ns = E0CAP;
    for (int i = t; i < ns; i += blockDim.x) {
        int s = slotnodes[i];
        slotmap[s] = i + 1;
        atomicOr(&bmS1[s >> 5], 1u << (s & 31));
    }
}

// Pass 3: LDS-bitmap probe for dst in S1 -> packed task records; mark srcs
// in bmNeed. Record: mlistS = s | slot<<17, mlistD = d.
__global__ void k_match(const int* __restrict__ src, const int* __restrict__ dst,
                        const int* __restrict__ slotmap,
                        const unsigned* __restrict__ bmS1, unsigned* __restrict__ bmNeed,
                        int* __restrict__ cnt, int* __restrict__ mlistS,
                        int* __restrict__ mlistD) {
    __shared__ unsigned sbm[NBMW];
    for (int i = threadIdx.x; i < NBMW; i += blockDim.x) sbm[i] = bmS1[i];
    __syncthreads();
    int tid = blockIdx.x * blockDim.x + threadIdx.x;
    int nth = gridDim.x * blockDim.x;
    const int4* dst4 = (const int4*)dst;
    const int n4 = N_EDGES / 4;
    for (int i = tid; i < n4; i += nth) {
        int4 dv = dst4[i];
        unsigned ds[4] = {(unsigned)dv.x, (unsigned)dv.y, (unsigned)dv.z, (unsigned)dv.w};
#pragma unroll
        for (int k = 0; k < 4; k++) {
            unsigned d = ds[k];
            if ((sbm[d >> 5] >> (d & 31)) & 1u) {
                int e = 4 * i + k;
                int s = src[e];
                int sl = slotmap[d] - 1;
                int p = atomicAdd(&cnt[2], 1);
                if (p < MCAP) {
                    mlistS[p] = s | (sl << 17);
                    mlistD[p] = (int)d;
                }
                atomicOr(&bmNeed[s >> 5], 1u << (s & 31));
            }
        }
    }
}

// Pass 4: filtered in-degree via LDS bitmap (S1 | need).
__global__ void k_deg_need(const int* __restrict__ dst, const unsigned* __restrict__ bmS1,
                           const unsigned* __restrict__ bmNeed, int* __restrict__ deg) {
    __shared__ unsigned sbm[NBMW];
    for (int i = threadIdx.x; i < NBMW; i += blockDim.x) sbm[i] = bmS1[i] | bmNeed[i];
    __syncthreads();
    int tid = blockIdx.x * blockDim.x + threadIdx.x;
    int nth = gridDim.x * blockDim.x;
    const int4* dst4 = (const int4*)dst;
    const int n4 = N_EDGES / 4;
    for (int i = tid; i < n4; i += nth) {
        int4 dv = dst4[i];
        unsigned ds[4] = {(unsigned)dv.x, (unsigned)dv.y, (unsigned)dv.z, (unsigned)dv.w};
#pragma unroll
        for (int k = 0; k < 4; k++) {
            unsigned d = ds[k];
            if ((sbm[d >> 5] >> (d & 31)) & 1u) atomicAdd(&deg[d], 1);
        }
    }
}

// Pass 5 (merged): edge contributions + last-block final epilogue.
// Contrib: 4 wave-tasks per 256-thr block (task = edge or self-loop, split
// into two K-halves of 64 rows). Broadcast x loads, fully unrolled.
// Epilogue: the LAST block to finish (atomic ticket on cnt[3], zeroed by
// k_scan0 two launches earlier -> no init race) runs layer-2 agg at node 0,
// W2 matvec, LSTM, FC. No dispatch-order assumption.
__global__ void k_contrib_final(
        const int* __restrict__ deg, const int* __restrict__ slotmap,
        int* __restrict__ cnt,
        const int* __restrict__ mlistS, const int* __restrict__ mlistD,
        const int* __restrict__ slotnodes, const int* __restrict__ edges0,
        const float* __restrict__ x, const float* __restrict__ W1,
        const float* __restrict__ b1, const float* __restrict__ W2,
        const float* __restrict__ b2, const float* __restrict__ w_ih,
        const float* __restrict__ b_ih, const float* __restrict__ b_hh,
        const float* __restrict__ fc_w, const float* __restrict__ fc_b,
        float* __restrict__ acc, float* __restrict__ out) {
    const int t = threadIdx.x;
    // ---- contrib phase ----
    {
        int m = cnt[2]; if (m > MCAP) m = MCAP;
        int ns = cnt[1]; if (ns > E0CAP) ns = E0CAP;
        const int vtotal = 2 * (m + ns);
        const int j = t & 63;        // output channel
        const int grp = t >> 6;      // wave within block
        for (int v = blockIdx.x * 4 + grp; v < vtotal; v += CF_BLOCKS * 4) {
            const int ii = v >> 1;
            const int kbase = (v & 1) << 6;  // 0 or 64
            int s, sl;
            float w;
            if (ii < m) {
                int sw = mlistS[ii];
                int d = mlistD[ii];
                s = sw & 0x1FFFF;
                sl = sw >> 17;
                w = dinv_of(deg[s]) * dinv_of(deg[d]);
            } else {
                sl = ii - m;
                s = slotnodes[sl];
                float dv = dinv_of(deg[s]);
                w = dv * dv;
            }
            const float* xp = x + (size_t)kbase * N_NODES + s;
            const float* wp = W1 + kbase * HG + j;
            float g = 0.f;
#pragma unroll
            for (int k = 0; k < 64; k++) {
                g = fmaf(xp[(size_t)k * N_NODES], wp[k * HG], g);
            }
            atomicAdd(&acc[sl * HG + j], g * w);
        }
    }
    // ---- last-block ticket ----
    __shared__ int amLast;
    __threadfence();                 // release our acc atomics
    __syncthreads();
    if (t == 0) {
        int prev = atomicAdd(&cnt[3], 1);
        amLast = (prev == (int)gridDim.x - 1);
    }
    __syncthreads();
    if (!amLast) return;
    __threadfence();                 // acquire all blocks' acc writes

    // ---- final epilogue (single block, 256 threads) ----
    __shared__ int   sh_sl[CHUNK];
    __shared__ float sh_w[CHUNK];
    __shared__ float partial[4][HG];
    __shared__ float aggv[HG];
    __shared__ float zv[HG];
    __shared__ float gates[4 * HG];
    __shared__ float hw[HG];
    const int ch = t & (HG - 1);
    const int grp = t >> 6;
    int n0 = cnt[0]; if (n0 > E0CAP) n0 = E0CAP;

    const float dinv0 = dinv_of(deg[0]);
    const float bch = b1[ch];

    float a = 0.f;
    for (int base = 0; base < n0; base += CHUNK) {
        int cn = n0 - base; if (cn > CHUNK) cn = CHUNK;
        __syncthreads();
        if (t < cn) {
            int s = edges0[base + t];
            sh_sl[t] = slotmap[s] - 1;
            sh_w[t] = dinv_of(deg[s]) * dinv0;
        }
        __syncthreads();
        for (int i = grp; i < cn; i += 4) {
            float h = acc[sh_sl[i] * HG + ch] + bch;
            a = fmaf(sh_w[i], (h > 0.f ? h : 0.f), a);
        }
    }
    partial[grp][ch] = a;
    __syncthreads();
    if (t < HG) {
        int sl0 = slotmap[0] - 1;
        float h0 = acc[sl0 * HG + t] + b1[t];
        float sg = dinv0 * dinv0 * (h0 > 0.f ? h0 : 0.f);
        sg += partial[0][t] + partial[1][t] + partial[2][t] + partial[3][t];
        aggv[t] = sg;
    }
    __syncthreads();

    if (t < HG) {
        float zz = b2[t];
#pragma unroll 8
        for (int k = 0; k < HG; k++) zz = fmaf(aggv[k], W2[k * HG + t], zz);
        zv[t] = zz;
    }
    __syncthreads();

    {
        float gt = b_ih[t] + b_hh[t];
#pragma unroll 8
        for (int jj = 0; jj < HG; jj++) gt = fmaf(zv[jj], w_ih[t * HG + jj], gt);
        gates[t] = gt;
    }
    __syncthreads();

    if (t < HG) {
        float ig = 1.f / (1.f + expf(-gates[t]));
        float gg = tanhf(gates[2 * HG + t]);
        float og = 1.f / (1.f + expf(-gates[3 * HG + t]));
        float c = ig * gg;
        float hy = og * tanhf(c);
        hw[t] = hy * fc_w[t];
    }
    __syncthreads();
    if (t == 0) {
        float y = fc_b[0];
        for (int jj = 0; jj < HG; jj++) y += hw[jj];
        out[0] = y;
    }
}

extern "C" void kernel_launch(void* const* d_in, const int* in_sizes, int n_in,
                              void* d_out, int out_size, void* d_ws, size_t ws_size,
                              hipStream_t stream) {
    const float* x    = (const float*)d_in[0];
    const int*   ei   = (const int*)d_in[1];
    const float* W1   = (const float*)d_in[2];
    const float* b1   = (const float*)d_in[3];
    const float* W2   = (const float*)d_in[4];
    const float* b2   = (const float*)d_in[5];
    const float* w_ih = (const float*)d_in[6];
    // d_in[7] = w_hh, unused (h0 = 0)
    const float* b_ih = (const float*)d_in[8];
    const float* b_hh = (const float*)d_in[9];
    const float* fc_w = (const float*)d_in[10];
    const float* fc_b = (const float*)d_in[11];
    float* out = (float*)d_out;

    const int* src = ei;
    const int* dst = ei + N_EDGES;

    char* ws = (char*)d_ws;
    int*      deg       = (int*)(ws + OFF_DEG);
    int*      slotmap   = (int*)(ws + OFF_SLOTMAP);
    int*      cnt       = (int*)(ws + OFF_CNT);
    float*    acc       = (float*)(ws + OFF_ACC);
    unsigned* bmS1      = (unsigned*)(ws + OFF_BMS1);
    unsigned* bmNeed    = (unsigned*)(ws + OFF_BMNEED);
    int*      bcnt      = (int*)(ws + OFF_BCNT);
    int*      blist     = (int*)(ws + OFF_BLIST);
    int*      edges0    = (int*)(ws + OFF_EDGES0);
    int*      slotnodes = (int*)(ws + OFF_SLOTNODE);
    int*      mlistS    = (int*)(ws + OFF_MLISTS);
    int*      mlistD    = (int*)(ws + OFF_MLISTD);

    k_scan0<<<SCAN_BLOCKS, 256, 0, stream>>>(src, dst, (int4*)ws, bcnt, blist);
    k_build_slots<<<1, 256, 0, stream>>>(bcnt, blist, edges0, slotnodes, slotmap, cnt, bmS1);
    k_match<<<SCAN_BLOCKS, 256, 0, stream>>>(src, dst, slotmap, bmS1, bmNeed, cnt,
                                             mlistS, mlistD);
    k_deg_need<<<SCAN_BLOCKS, 256, 0, stream>>>(dst, bmS1, bmNeed, deg);
    k_contrib_final<<<CF_BLOCKS, 256, 0, stream>>>(deg, slotmap, cnt, mlistS, mlistD,
                                                   slotnodes, edges0, x, W1, b1, W2, b2,
                                                   w_ih, b_ih, b_hh, fc_w, fc_b, acc, out);
}

// Round 3
// 171.026 us; speedup vs baseline: 3.7190x; 1.4499x over previous
//
#include <hip/hip_runtime.h>
#include <math.h>

#define N_NODES 100000
#define N_EDGES 3200000
#define IN_DIM 128
#define HG 64

#define E0CAP 2048      // capacity for edges into node 0 (expected ~32)
#define MCAP  65536     // capacity for edges into S1 nodes (expected ~1100)
#define NBMW  3125      // bitmap words: ceil(100000/32)
#define SCAN_BLOCKS 1024 // proven round-0 grid for the dst scans
#define BLK_E0 16       // per-block capacity for dst==0 hits
#define CF_BLOCKS 1024  // contrib+final grid: 4 wave-tasks per block

// workspace layout; [0, WS_ZERO_BYTES) zeroed by k_scan0 grid-stride
#define OFF_DEG       0u          // int[N_NODES]            400000
#define OFF_SLOTMAP   400000u     // int[N_NODES]            400000
#define OFF_CNT       800000u     // int[8]: n0,ns,m,done    32
#define OFF_ACC       800032u     // float[E0CAP*HG]         524288
#define OFF_BMS1      1324320u    // uint[NBMW] pad          12544
#define OFF_BMNEED    1336864u    // uint[NBMW] pad          12544
#define WS_ZERO_BYTES 1349408u
#define OFF_BCNT      1349408u    // int[SCAN_BLOCKS]        4096
#define OFF_BLIST     1353504u    // int[SCAN_BLOCKS*BLK_E0] 65536
#define OFF_EDGES0    1419040u    // int[E0CAP]              8192
#define OFF_SLOTNODE  1427232u    // int[E0CAP]              8192
#define OFF_MLISTS    1435424u    // int[MCAP]  s | slot<<17 262144
#define OFF_MLISTD    1697568u    // int[MCAP]  d            262144

#define CHUNK 256

__device__ __forceinline__ float dinv_of(int degv) {
    // reference: deg = indeg + 1 (self loop), dinv = 1/sqrt(deg), always >= 1
    return 1.0f / sqrtf((float)(degv + 1));
}

// Pass 1: zero ws counters/acc/bitmaps (replaces hipMemsetAsync) and scan dst
// for edges into node 0, compacting per-block (no global counter).
__global__ void k_scan0(const int* __restrict__ src, const int* __restrict__ dst,
                        int4* __restrict__ zbase, int* __restrict__ bcnt,
                        int* __restrict__ blist) {
    __shared__ int lcnt;
    __shared__ int lsrc[BLK_E0];
    if (threadIdx.x == 0) lcnt = 0;
    __syncthreads();
    int tid = blockIdx.x * blockDim.x + threadIdx.x;
    int nth = gridDim.x * blockDim.x;
    const int nz = WS_ZERO_BYTES / 16;
    int4 z; z.x = 0; z.y = 0; z.z = 0; z.w = 0;
    for (int i = tid; i < nz; i += nth) zbase[i] = z;
    const int4* dst4 = (const int4*)dst;
    const int n4 = N_EDGES / 4;
    for (int i = tid; i < n4; i += nth) {
        int4 dv = dst4[i];
        int ds[4] = {dv.x, dv.y, dv.z, dv.w};
#pragma unroll
        for (int k = 0; k < 4; k++) {
            if (ds[k] == 0) {
                int p = atomicAdd(&lcnt, 1);
                if (p < BLK_E0) lsrc[p] = src[4 * i + k];
            }
        }
    }
    __syncthreads();
    int c = lcnt; if (c > BLK_E0) c = BLK_E0;
    if (threadIdx.x == 0) bcnt[blockIdx.x] = c;
    for (int i = threadIdx.x; i < c; i += blockDim.x)
        blist[blockIdx.x * BLK_E0 + i] = lsrc[i];
}

// Pass 2 (1 block): gather per-block lists -> dense edges0, dedupe -> slots,
// build S1 bitmap.
__global__ void k_build_slots(const int* __restrict__ bcnt, const int* __restrict__ blist,
                              int* __restrict__ edges0, int* __restrict__ slotnodes,
                              int* __restrict__ slotmap, int* __restrict__ cnt,
                              unsigned* __restrict__ bmS1) {
    const int t = threadIdx.x;
    for (int b = t; b < SCAN_BLOCKS; b += blockDim.x) {
        int c = bcnt[b];
        if (c > 0) {
            int p = atomicAdd(&cnt[0], c);
            for (int j = 0; j < c && p + j < E0CAP; j++)
                edges0[p + j] = blist[b * BLK_E0 + j];
        }
    }
    __syncthreads();
    int n0 = atomicAdd(&cnt[0], 0); if (n0 > E0CAP) n0 = E0CAP;
    for (int i = t; i < n0 + 1; i += blockDim.x) {
        int s = (i == n0) ? 0 : edges0[i];   // +node 0 itself
        if (atomicCAS(&slotmap[s], 0, 1) == 0) {
            int p = atomicAdd(&cnt[1], 1);
            if (p < E0CAP) slotnodes[p] = s;
        }
    }
    __syncthreads();
    int ns = atomicAdd(&cnt[1], 0); if (ns > E0CAP) ns = E0CAP;
    for (int i = t; i < ns; i += blockDim.x) {
        int s = slotnodes[i];
        slotmap[s] = i + 1;
        atomicOr(&bmS1[s >> 5], 1u << (s & 31));
    }
}

// Pass 3: LDS-bitmap probe for dst in S1 -> packed task records; mark srcs
// in bmNeed. Record: mlistS = s | slot<<17, mlistD = d.
__global__ void k_match(const int* __restrict__ src, const int* __restrict__ dst,
                        const int* __restrict__ slotmap,
                        const unsigned* __restrict__ bmS1, unsigned* __restrict__ bmNeed,
                        int* __restrict__ cnt, int* __restrict__ mlistS,
                        int* __restrict__ mlistD) {
    __shared__ unsigned sbm[NBMW];
    for (int i = threadIdx.x; i < NBMW; i += blockDim.x) sbm[i] = bmS1[i];
    __syncthreads();
    int tid = blockIdx.x * blockDim.x + threadIdx.x;
    int nth = gridDim.x * blockDim.x;
    const int4* dst4 = (const int4*)dst;
    const int n4 = N_EDGES / 4;
    for (int i = tid; i < n4; i += nth) {
        int4 dv = dst4[i];
        unsigned ds[4] = {(unsigned)dv.x, (unsigned)dv.y, (unsigned)dv.z, (unsigned)dv.w};
#pragma unroll
        for (int k = 0; k < 4; k++) {
            unsigned d = ds[k];
            if ((sbm[d >> 5] >> (d & 31)) & 1u) {
                int e = 4 * i + k;
                int s = src[e];
                int sl = slotmap[d] - 1;
                int p = atomicAdd(&cnt[2], 1);
                if (p < MCAP) {
                    mlistS[p] = s | (sl << 17);
                    mlistD[p] = (int)d;
                }
                atomicOr(&bmNeed[s >> 5], 1u << (s & 31));
            }
        }
    }
}

// Pass 4: filtered in-degree via LDS bitmap (S1 | need).
__global__ void k_deg_need(const int* __restrict__ dst, const unsigned* __restrict__ bmS1,
                           const unsigned* __restrict__ bmNeed, int* __restrict__ deg) {
    __shared__ unsigned sbm[NBMW];
    for (int i = threadIdx.x; i < NBMW; i += blockDim.x) sbm[i] = bmS1[i] | bmNeed[i];
    __syncthreads();
    int tid = blockIdx.x * blockDim.x + threadIdx.x;
    int nth = gridDim.x * blockDim.x;
    const int4* dst4 = (const int4*)dst;
    const int n4 = N_EDGES / 4;
    for (int i = tid; i < n4; i += nth) {
        int4 dv = dst4[i];
        unsigned ds[4] = {(unsigned)dv.x, (unsigned)dv.y, (unsigned)dv.z, (unsigned)dv.w};
#pragma unroll
        for (int k = 0; k < 4; k++) {
            unsigned d = ds[k];
            if ((sbm[d >> 5] >> (d & 31)) & 1u) atomicAdd(&deg[d], 1);
        }
    }
}

// Pass 5 (merged): edge contributions + last-block final epilogue.
// Sync protocol (round-2 lesson: NO all-blocks __threadfence -- that emits
// buffer_wbl2/buffer_inv per wave = ~1024 serialized L2 walks per XCD =
// ~105us of idle):
//   release: per-wave `s_waitcnt vmcnt(0)` -- acc atomics are vmem ops, so
//            vmcnt(0) means they completed at the coherent point -- then
//            __syncthreads, then one ticket atomic per block.
//   acquire: ONE __threadfence() in the single last block (4 waves) before
//            its plain reads of acc.
__global__ void k_contrib_final(
        const int* __restrict__ deg, const int* __restrict__ slotmap,
        int* __restrict__ cnt,
        const int* __restrict__ mlistS, const int* __restrict__ mlistD,
        const int* __restrict__ slotnodes, const int* __restrict__ edges0,
        const float* __restrict__ x, const float* __restrict__ W1,
        const float* __restrict__ b1, const float* __restrict__ W2,
        const float* __restrict__ b2, const float* __restrict__ w_ih,
        const float* __restrict__ b_ih, const float* __restrict__ b_hh,
        const float* __restrict__ fc_w, const float* __restrict__ fc_b,
        float* __restrict__ acc, float* __restrict__ out) {
    const int t = threadIdx.x;
    // ---- contrib phase ----
    {
        int m = cnt[2]; if (m > MCAP) m = MCAP;
        int ns = cnt[1]; if (ns > E0CAP) ns = E0CAP;
        const int vtotal = 2 * (m + ns);
        const int j = t & 63;        // output channel
        const int grp = t >> 6;      // wave within block
        for (int v = blockIdx.x * 4 + grp; v < vtotal; v += CF_BLOCKS * 4) {
            const int ii = v >> 1;
            const int kbase = (v & 1) << 6;  // 0 or 64
            int s, sl;
            float w;
            if (ii < m) {
                int sw = mlistS[ii];
                int d = mlistD[ii];
                s = sw & 0x1FFFF;
                sl = sw >> 17;
                w = dinv_of(deg[s]) * dinv_of(deg[d]);
            } else {
                sl = ii - m;
                s = slotnodes[sl];
                float dv = dinv_of(deg[s]);
                w = dv * dv;
            }
            const float* xp = x + (size_t)kbase * N_NODES + s;
            const float* wp = W1 + kbase * HG + j;
            float g = 0.f;
#pragma unroll
            for (int k = 0; k < 64; k++) {
                g = fmaf(xp[(size_t)k * N_NODES], wp[k * HG], g);
            }
            atomicAdd(&acc[sl * HG + j], g * w);
        }
    }
    // ---- last-block ticket (cheap release: per-wave vmcnt drain) ----
    __shared__ int amLast;
    asm volatile("s_waitcnt vmcnt(0)" ::: "memory");
    __syncthreads();
    if (t == 0) {
        int prev = atomicAdd(&cnt[3], 1);
        amLast = (prev == (int)gridDim.x - 1);
    }
    __syncthreads();
    if (!amLast) return;
    __threadfence();                 // acquire (single block only)

    // ---- final epilogue (single block, 256 threads) ----
    __shared__ int   sh_sl[CHUNK];
    __shared__ float sh_w[CHUNK];
    __shared__ float partial[4][HG];
    __shared__ float aggv[HG];
    __shared__ float zv[HG];
    __shared__ float gates[4 * HG];
    __shared__ float hw[HG];
    const int ch = t & (HG - 1);
    const int grp = t >> 6;
    int n0 = cnt[0]; if (n0 > E0CAP) n0 = E0CAP;

    const float dinv0 = dinv_of(deg[0]);
    const float bch = b1[ch];

    float a = 0.f;
    for (int base = 0; base < n0; base += CHUNK) {
        int cn = n0 - base; if (cn > CHUNK) cn = CHUNK;
        __syncthreads();
        if (t < cn) {
            int s = edges0[base + t];
            sh_sl[t] = slotmap[s] - 1;
            sh_w[t] = dinv_of(deg[s]) * dinv0;
        }
        __syncthreads();
        for (int i = grp; i < cn; i += 4) {
            float h = acc[sh_sl[i] * HG + ch] + bch;
            a = fmaf(sh_w[i], (h > 0.f ? h : 0.f), a);
        }
    }
    partial[grp][ch] = a;
    __syncthreads();
    if (t < HG) {
        int sl0 = slotmap[0] - 1;
        float h0 = acc[sl0 * HG + t] + b1[t];
        float sg = dinv0 * dinv0 * (h0 > 0.f ? h0 : 0.f);
        sg += partial[0][t] + partial[1][t] + partial[2][t] + partial[3][t];
        aggv[t] = sg;
    }
    __syncthreads();

    if (t < HG) {
        float zz = b2[t];
#pragma unroll 8
        for (int k = 0; k < HG; k++) zz = fmaf(aggv[k], W2[k * HG + t], zz);
        zv[t] = zz;
    }
    __syncthreads();

    {
        float gt = b_ih[t] + b_hh[t];
#pragma unroll 8
        for (int jj = 0; jj < HG; jj++) gt = fmaf(zv[jj], w_ih[t * HG + jj], gt);
        gates[t] = gt;
    }
    __syncthreads();

    if (t < HG) {
        float ig = 1.f / (1.f + expf(-gates[t]));
        float gg = tanhf(gates[2 * HG + t]);
        float og = 1.f / (1.f + expf(-gates[3 * HG + t]));
        float c = ig * gg;
        float hy = og * tanhf(c);
        hw[t] = hy * fc_w[t];
    }
    __syncthreads();
    if (t == 0) {
        float y = fc_b[0];
        for (int jj = 0; jj < HG; jj++) y += hw[jj];
        out[0] = y;
    }
}

extern "C" void kernel_launch(void* const* d_in, const int* in_sizes, int n_in,
                              void* d_out, int out_size, void* d_ws, size_t ws_size,
                              hipStream_t stream) {
    const float* x    = (const float*)d_in[0];
    const int*   ei   = (const int*)d_in[1];
    const float* W1   = (const float*)d_in[2];
    const float* b1   = (const float*)d_in[3];
    const float* W2   = (const float*)d_in[4];
    const float* b2   = (const float*)d_in[5];
    const float* w_ih = (const float*)d_in[6];
    // d_in[7] = w_hh, unused (h0 = 0)
    const float* b_ih = (const float*)d_in[8];
    const float* b_hh = (const float*)d_in[9];
    const float* fc_w = (const float*)d_in[10];
    const float* fc_b = (const float*)d_in[11];
    float* out = (float*)d_out;

    const int* src = ei;
    const int* dst = ei + N_EDGES;

    char* ws = (char*)d_ws;
    int*      deg       = (int*)(ws + OFF_DEG);
    int*      slotmap   = (int*)(ws + OFF_SLOTMAP);
    int*      cnt       = (int*)(ws + OFF_CNT);
    float*    acc       = (float*)(ws + OFF_ACC);
    unsigned* bmS1      = (unsigned*)(ws + OFF_BMS1);
    unsigned* bmNeed    = (unsigned*)(ws + OFF_BMNEED);
    int*      bcnt      = (int*)(ws + OFF_BCNT);
    int*      blist     = (int*)(ws + OFF_BLIST);
    int*      edges0    = (int*)(ws + OFF_EDGES0);
    int*      slotnodes = (int*)(ws + OFF_SLOTNODE);
    int*      mlistS    = (int*)(ws + OFF_MLISTS);
    int*      mlistD    = (int*)(ws + OFF_MLISTD);

    k_scan0<<<SCAN_BLOCKS, 256, 0, stream>>>(src, dst, (int4*)ws, bcnt, blist);
    k_build_slots<<<1, 256, 0, stream>>>(bcnt, blist, edges0, slotnodes, slotmap, cnt, bmS1);
    k_match<<<SCAN_BLOCKS, 256, 0, stream>>>(src, dst, slotmap, bmS1, bmNeed, cnt,
                                             mlistS, mlistD);
    k_deg_need<<<SCAN_BLOCKS, 256, 0, stream>>>(dst, bmS1, bmNeed, deg);
    k_contrib_final<<<CF_BLOCKS, 256, 0, stream>>>(deg, slotmap, cnt, mlistS, mlistD,
                                                   slotnodes, edges0, x, W1, b1, W2, b2,
                                                   w_ih, b_ih, b_hh, fc_w, fc_b, acc, out);
}